// Round 1
// baseline (2276.673 us; speedup 1.0000x reference)
//
#include <hip/hip_runtime.h>

#define NP 784
#define DIM 384
#define NL 200000
#define WTOP_BLOCKS 512

__device__ __forceinline__ unsigned long long packdj(float d2, int j) {
  return ((unsigned long long)__float_as_uint(d2) << 32) | (unsigned int)j;
}

__device__ __forceinline__ void ins3(unsigned long long &t0, unsigned long long &t1,
                                     unsigned long long &t2, unsigned long long p) {
  if (p < t0) { t2 = t1; t1 = t0; t0 = p; }
  else if (p < t1) { t2 = t1; t1 = p; }
  else if (p < t2) { t2 = p; }
}

// ---------------- norms: a2[i] = |patch_i|^2, b2[j] = |lib_j|^2 ----------------
__global__ __launch_bounds__(256) void k_norms(const float* __restrict__ patch,
                                               const float* __restrict__ lib,
                                               float* __restrict__ a2,
                                               float* __restrict__ b2) {
  int wave = (blockIdx.x << 2) | (threadIdx.x >> 6);
  int lane = threadIdx.x & 63;
  const int NR = NL + NP;
  if (wave >= NR) return;
  const float* src = (wave < NL) ? (lib + (size_t)wave * DIM)
                                 : (patch + (size_t)(wave - NL) * DIM);
  float s = 0.f;
#pragma unroll
  for (int m = 0; m < 6; ++m) { float v = src[lane + (m << 6)]; s += v * v; }
#pragma unroll
  for (int m = 1; m < 64; m <<= 1) s += __shfl_xor(s, m);
  if (lane == 0) { if (wave < NL) b2[wave] = s; else a2[wave - NL] = s; }
}

// ------------- main: tiled fp32 GEMM + on-the-fly min over lib (packed) -------------
__global__ __launch_bounds__(256) void k_distmin(const float* __restrict__ patch,
                                                 const float* __restrict__ lib,
                                                 const float* __restrict__ a2,
                                                 const float* __restrict__ b2,
                                                 unsigned long long* __restrict__ pmin) {
  __shared__ float As[16][68];  // [k][i], stride 68 floats: 16B-aligned rows, conflict-friendly
  __shared__ float Bs[16][68];  // [k][j]
  const int t = threadIdx.x;
  const int lr = t >> 2;          // 0..63: tile row for staging
  const int lc = (t & 3) << 2;    // 0,4,8,12: k-offset for staging (float4)
  const int ti = t >> 4;          // 0..15
  const int tj = t & 15;          // 0..15
  const int i0 = blockIdx.y << 6;
  const int j0 = blockIdx.x << 6;
  const bool a_ok = (i0 + lr) < NP;
  const float* ap = patch + (size_t)(i0 + lr) * DIM + lc;
  const float* bp = lib + (size_t)(j0 + lr) * DIM + lc;

  float acc[4][4] = {};
  for (int k0 = 0; k0 < DIM; k0 += 16) {
    float4 avv = make_float4(0.f, 0.f, 0.f, 0.f);
    if (a_ok) avv = *(const float4*)(ap + k0);
    float4 bvv = *(const float4*)(bp + k0);
    __syncthreads();
    As[lc + 0][lr] = avv.x; As[lc + 1][lr] = avv.y;
    As[lc + 2][lr] = avv.z; As[lc + 3][lr] = avv.w;
    Bs[lc + 0][lr] = bvv.x; Bs[lc + 1][lr] = bvv.y;
    Bs[lc + 2][lr] = bvv.z; Bs[lc + 3][lr] = bvv.w;
    __syncthreads();
#pragma unroll
    for (int kk = 0; kk < 16; ++kk) {
      float4 a = *(const float4*)&As[kk][ti << 2];
      float4 b = *(const float4*)&Bs[kk][tj << 2];
      acc[0][0] += a.x * b.x; acc[0][1] += a.x * b.y; acc[0][2] += a.x * b.z; acc[0][3] += a.x * b.w;
      acc[1][0] += a.y * b.x; acc[1][1] += a.y * b.y; acc[1][2] += a.y * b.z; acc[1][3] += a.y * b.w;
      acc[2][0] += a.z * b.x; acc[2][1] += a.z * b.y; acc[2][2] += a.z * b.z; acc[2][3] += a.z * b.w;
      acc[3][0] += a.w * b.x; acc[3][1] += a.w * b.y; acc[3][2] += a.w * b.z; acc[3][3] += a.w * b.w;
    }
  }

#pragma unroll
  for (int r = 0; r < 4; ++r) {
    int i = i0 + (ti << 2) + r;   // uniform across the 16 lanes of a tj-group
    unsigned long long best = ~0ull;
    if (i < NP) {
      float ai = a2[i];
#pragma unroll
      for (int c = 0; c < 4; ++c) {
        int j = j0 + (tj << 2) + c;
        float d2 = fmaxf(ai + b2[j] - 2.f * acc[r][c], 0.f);
        unsigned long long p = packdj(d2, j);
        best = (p < best) ? p : best;
      }
    }
#pragma unroll
    for (int m = 1; m < 16; m <<= 1) {
      unsigned long long o = __shfl_xor(best, m);
      best = (o < best) ? o : best;
    }
    if (tj == 0 && i < NP) atomicMin(pmin + i, best);
  }
}

// ---------- finalize1: min_val = sqrt(d2min); s_star/s_idx via argmax (jnp tie-break) ----------
__global__ __launch_bounds__(256) void k_final1(const unsigned long long* __restrict__ pmin,
                                                float* __restrict__ minval,
                                                float* __restrict__ scalf,
                                                int* __restrict__ scali) {
  __shared__ float sv[256];
  __shared__ int si[256];
  int t = threadIdx.x;
  float bv = -1.f; int bi = 1 << 30;
  for (int i = t; i < NP; i += 256) {
    unsigned long long p = pmin[i];
    float d2 = __uint_as_float((unsigned int)(p >> 32));
    float v = sqrtf(d2);
    minval[i] = v;
    if (v > bv) { bv = v; bi = i; }  // strict > keeps first (smallest i) on ties
  }
  sv[t] = bv; si[t] = bi;
  __syncthreads();
  for (int s = 128; s > 0; s >>= 1) {
    if (t < s) {
      if (sv[t + s] > sv[t] || (sv[t + s] == sv[t] && si[t + s] < si[t])) {
        sv[t] = sv[t + s]; si[t] = si[t + s];
      }
    }
    __syncthreads();
  }
  if (t == 0) {
    scalf[0] = sv[0];                                             // s_star
    scali[0] = si[0];                                             // s_idx
    scali[1] = (int)(unsigned int)(pmin[si[0]] & 0xFFFFFFFFull);  // jstar = min_idx[s_idx]
  }
}

// ---------- w_dist from m_star to all lib rows; per-block top-3 ----------
__global__ __launch_bounds__(256) void k_wtop(const float* __restrict__ lib,
                                              const int* __restrict__ scali,
                                              unsigned long long* __restrict__ top3) {
  __shared__ unsigned long long sm[12];
  int wave = threadIdx.x >> 6, lane = threadIdx.x & 63;
  int jstar = scali[1];
  const float* ms = lib + (size_t)jstar * DIM;
  float m[6];
#pragma unroll
  for (int q = 0; q < 6; ++q) m[q] = ms[lane + (q << 6)];
  unsigned long long t0 = ~0ull, t1 = ~0ull, t2 = ~0ull;
  int gw = (blockIdx.x << 2) | wave;
  for (int j = gw; j < NL; j += WTOP_BLOCKS * 4) {
    const float* bp = lib + (size_t)j * DIM;
    float s = 0.f;
#pragma unroll
    for (int q = 0; q < 6; ++q) { float d = bp[lane + (q << 6)] - m[q]; s += d * d; }
#pragma unroll
    for (int mm = 1; mm < 64; mm <<= 1) s += __shfl_xor(s, mm);
    ins3(t0, t1, t2, packdj(fmaxf(s, 0.f), j));
  }
  if (lane == 0) { sm[wave * 3] = t0; sm[wave * 3 + 1] = t1; sm[wave * 3 + 2] = t2; }
  __syncthreads();
  if (threadIdx.x == 0) {
    unsigned long long a0 = ~0ull, a1 = ~0ull, a2v = ~0ull;
    for (int e = 0; e < 12; ++e) ins3(a0, a1, a2v, sm[e]);
    top3[blockIdx.x * 3 + 0] = a0;
    top3[blockIdx.x * 3 + 1] = a1;
    top3[blockIdx.x * 3 + 2] = a2v;
  }
}

// ---------- final s: merge top3, two ||m_test - knn|| distances, w formula ----------
__global__ __launch_bounds__(256) void k_finals(const float* __restrict__ patch,
                                                const float* __restrict__ lib,
                                                const unsigned long long* __restrict__ top3,
                                                const float* __restrict__ scalf,
                                                const int* __restrict__ scali,
                                                float* __restrict__ out) {
  __shared__ unsigned long long sm[768];
  __shared__ int snn[2];
  __shared__ float sd[2];
  int t = threadIdx.x;
  unsigned long long t0 = ~0ull, t1 = ~0ull, t2 = ~0ull;
  for (int e = t; e < WTOP_BLOCKS * 3; e += 256) ins3(t0, t1, t2, top3[e]);
  sm[t] = t0; sm[256 + t] = t1; sm[512 + t] = t2;
  __syncthreads();
  if (t == 0) {
    unsigned long long a0 = ~0ull, a1 = ~0ull, a2v = ~0ull;
    for (int e = 0; e < 768; ++e) ins3(a0, a1, a2v, sm[e]);
    snn[0] = (int)(unsigned int)(a1 & 0xFFFFFFFFull);  // nn_idx[1]
    snn[1] = (int)(unsigned int)(a2v & 0xFFFFFFFFull); // nn_idx[2]
  }
  __syncthreads();
  if (t < 128) {
    int wv = t >> 6, lane = t & 63;
    const float* mt = patch + (size_t)scali[0] * DIM;
    const float* bp = lib + (size_t)snn[wv] * DIM;
    float s = 0.f;
#pragma unroll
    for (int q = 0; q < 6; ++q) {
      float d = mt[lane + (q << 6)] - bp[lane + (q << 6)];
      s += d * d;
    }
#pragma unroll
    for (int mm = 1; mm < 64; mm <<= 1) s += __shfl_xor(s, mm);
    if (lane == 0) sd[wv] = sqrtf(fmaxf(s, 0.f));
  }
  __syncthreads();
  if (t == 0) {
    const float Ds = 19.595917942265423f;  // sqrt(384)
    float sstar = scalf[0];
    float w = 1.f - expf(sstar / Ds) / (expf(sd[0] / Ds) + expf(sd[1] / Ds));
    out[0] = w * sstar;
  }
}

// ---------- bilinear 28x28 -> 224x224 (jax.image.resize 'bilinear' semantics) ----------
__global__ __launch_bounds__(256) void k_resize(const float* __restrict__ mv,
                                                float* __restrict__ out) {
  int o = blockIdx.x * 256 + threadIdx.x;
  if (o >= 224 * 224) return;
  int y = o / 224, x = o - y * 224;
  float sy = (y + 0.5f) * 0.125f - 0.5f;
  float sx = (x + 0.5f) * 0.125f - 0.5f;
  int y0 = (int)floorf(sy); float fy = sy - (float)y0;
  int x0 = (int)floorf(sx); float fx = sx - (float)x0;
  int y0c = max(y0, 0), y1c = min(y0 + 1, 27);
  int x0c = max(x0, 0), x1c = min(x0 + 1, 27);
  float v00 = mv[y0c * 28 + x0c], v01 = mv[y0c * 28 + x1c];
  float v10 = mv[y1c * 28 + x0c], v11 = mv[y1c * 28 + x1c];
  float v0 = v00 + fx * (v01 - v00);
  float v1 = v10 + fx * (v11 - v10);
  out[1 + o] = v0 + fy * (v1 - v0);
}

extern "C" void kernel_launch(void* const* d_in, const int* in_sizes, int n_in,
                              void* d_out, int out_size, void* d_ws, size_t ws_size,
                              hipStream_t stream) {
  const float* patch = (const float*)d_in[0];
  const float* lib = (const float*)d_in[1];
  float* out = (float*)d_out;
  char* ws = (char*)d_ws;

  // workspace layout (bytes):
  float* b2 = (float*)ws;                                           // 200000 f -> 800000
  float* a2 = (float*)(ws + 800000);                                // 784 f   -> 803136
  unsigned long long* pmin = (unsigned long long*)(ws + 803200);    // 784 u64 -> 809472
  unsigned long long* top3 = (unsigned long long*)(ws + 809472);    // 512*3 u64 -> 821760
  float* minval = (float*)(ws + 821760);                            // 784 f   -> 824896
  float* scalf = (float*)(ws + 824896);                             // 4 f
  int* scali = (int*)(ws + 824912);                                 // 4 i

  // init packed mins to u64-max (0xFF bytes)
  hipMemsetAsync(pmin, 0xFF, NP * sizeof(unsigned long long), stream);

  // norms: one wave per row, (200000+784)/4 waves per 256-thread block
  k_norms<<<(NL + NP + 3) / 4, 256, 0, stream>>>(patch, lib, a2, b2);

  // main distance + min: 64x64 tiles
  dim3 grid(NL / 64, (NP + 63) / 64);  // 3125 x 13
  k_distmin<<<grid, 256, 0, stream>>>(patch, lib, a2, b2, pmin);

  k_final1<<<1, 256, 0, stream>>>(pmin, minval, scalf, scali);

  k_wtop<<<WTOP_BLOCKS, 256, 0, stream>>>(lib, scali, top3);

  k_finals<<<1, 256, 0, stream>>>(patch, lib, top3, scalf, scali, out);

  k_resize<<<(224 * 224 + 255) / 256, 256, 0, stream>>>(minval, out);
}

// Round 2
// 803.971 us; speedup vs baseline: 2.8318x; 2.8318x over previous
//
#include <hip/hip_runtime.h>

#define NP 784
#define DIM 384
#define NL 200000
#define WTOP_BLOCKS 512

#define BM 128
#define BN 128
#define MTILES 7
#define NTILES 1563
#define MPAD (MTILES * BM)    // 896
#define NLPAD (NTILES * BN)   // 200064
#define PCOLS (NTILES * 2)    // partial-min columns per i

typedef __attribute__((ext_vector_type(8))) short short8;
typedef __attribute__((ext_vector_type(4))) float f32x4;

__device__ __forceinline__ unsigned long long packdj(float d2, int j) {
  return ((unsigned long long)__float_as_uint(d2) << 32) | (unsigned int)j;
}

__device__ __forceinline__ void ins3(unsigned long long &t0, unsigned long long &t1,
                                     unsigned long long &t2, unsigned long long p) {
  if (p < t0) { t2 = t1; t1 = t0; t0 = p; }
  else if (p < t1) { t2 = t1; t1 = p; }
  else if (p < t2) { t2 = p; }
}

__device__ __forceinline__ unsigned short bf16rn(float x) {
  unsigned u = __float_as_uint(x);
  unsigned r = (u + 0x7fffu + ((u >> 16) & 1u)) >> 16;
  return (unsigned short)r;
}

// ================= prep A: patch -> Ah/Al bf16 planes + a2 (exact fp32) =================
__global__ __launch_bounds__(256) void k_prep_a(const float* __restrict__ patch,
                                                unsigned short* __restrict__ Ah,
                                                unsigned short* __restrict__ Al,
                                                float* __restrict__ a2) {
  int i = (blockIdx.x << 2) | (threadIdx.x >> 6);
  int lane = threadIdx.x & 63;
  if (i >= MPAD) return;
  if (i < NP) {
    float s = 0.f;
#pragma unroll
    for (int q = 0; q < 6; ++q) {
      float x = patch[(size_t)i * DIM + lane + (q << 6)];
      s += x * x;
      unsigned short bh = bf16rn(x);
      float fh = __uint_as_float(((unsigned)bh) << 16);
      unsigned short bl = bf16rn(x - fh);
      Ah[(size_t)i * DIM + lane + (q << 6)] = bh;
      Al[(size_t)i * DIM + lane + (q << 6)] = bl;
    }
#pragma unroll
    for (int m = 1; m < 64; m <<= 1) s += __shfl_xor(s, m);
    if (lane == 0) a2[i] = s;
  } else {
#pragma unroll
    for (int q = 0; q < 6; ++q) {
      Ah[(size_t)i * DIM + lane + (q << 6)] = 0;
      Al[(size_t)i * DIM + lane + (q << 6)] = 0;
    }
  }
}

// ================= prep B: lib -> Bh/Bl bf16 planes + b2 (pad rows: zero, b2=+inf) ======
__global__ __launch_bounds__(256) void k_prep_b(const float* __restrict__ lib,
                                                unsigned short* __restrict__ Bh,
                                                unsigned short* __restrict__ Bl,
                                                float* __restrict__ b2) {
  int j = (blockIdx.x << 2) | (threadIdx.x >> 6);
  int lane = threadIdx.x & 63;
  if (j >= NLPAD) return;
  if (j < NL) {
    float s = 0.f;
#pragma unroll
    for (int q = 0; q < 6; ++q) {
      float x = lib[(size_t)j * DIM + lane + (q << 6)];
      s += x * x;
      unsigned short bh = bf16rn(x);
      float fh = __uint_as_float(((unsigned)bh) << 16);
      unsigned short bl = bf16rn(x - fh);
      Bh[(size_t)j * DIM + lane + (q << 6)] = bh;
      Bl[(size_t)j * DIM + lane + (q << 6)] = bl;
    }
#pragma unroll
    for (int m = 1; m < 64; m <<= 1) s += __shfl_xor(s, m);
    if (lane == 0) b2[j] = s;
  } else {
#pragma unroll
    for (int q = 0; q < 6; ++q) {
      Bh[(size_t)j * DIM + lane + (q << 6)] = 0;
      Bl[(size_t)j * DIM + lane + (q << 6)] = 0;
    }
    if (lane == 0) b2[j] = INFINITY;
  }
}

// ============== main: 128x128 MFMA GEMM (3-term bf16 split) + fused packed min ==========
__global__ __launch_bounds__(256, 2) void k_gemm(const unsigned short* __restrict__ Ah,
                                                 const unsigned short* __restrict__ Al,
                                                 const unsigned short* __restrict__ Bh,
                                                 const unsigned short* __restrict__ Bl,
                                                 const float* __restrict__ a2,
                                                 const float* __restrict__ b2,
                                                 unsigned long long* __restrict__ partial) {
  __shared__ short sAh[4096], sAl[4096], sBh[4096], sBl[4096];

  // bijective XCD swizzle; M-tiles of one N-tile adjacent (B-slice L2 reuse)
  const int TOT = MTILES * NTILES;           // 10941
  const int q8 = TOT >> 3, r8 = TOT & 7;     // 1367, 5
  int xcd = blockIdx.x & 7, seq = blockIdx.x >> 3;
  int wg = (xcd < r8 ? xcd * (q8 + 1) : r8 * (q8 + 1) + (xcd - r8) * q8) + seq;
  int ntile = wg / MTILES;
  int mtile = wg - ntile * MTILES;
  const int i0 = mtile * BM;
  const int j0 = ntile * BN;

  const int t = threadIdx.x;
  const int w = t >> 6, lane = t & 63;
  const int wr = w >> 1, wc = w & 1;         // wave -> 64x64 sub-tile
  const int lrow = lane & 15, lk = lane >> 4;

  // staging sources (pre-swizzled k-chunk so linear LDS + swizzled read agree)
  const unsigned short* srcs[8];
  short* dsts[8];
  {
    int dbase = w << 10;  // w*1024 shorts = 2KB
#pragma unroll
    for (int p = 0; p < 2; ++p) {
      int c = (w << 7) + (p << 6) + lane;
      int row = c >> 2, kb = c & 3;
      int ks = ((kb ^ ((row >> 1) & 3)) << 3);
      size_t aoff = (size_t)(i0 + row) * DIM + ks;
      size_t boff = (size_t)(j0 + row) * DIM + ks;
      srcs[0 + p] = Ah + aoff; srcs[2 + p] = Al + aoff;
      srcs[4 + p] = Bh + boff; srcs[6 + p] = Bl + boff;
      dsts[0 + p] = sAh + dbase + (p << 9);
      dsts[2 + p] = sAl + dbase + (p << 9);
      dsts[4 + p] = sBh + dbase + (p << 9);
      dsts[6 + p] = sBl + dbase + (p << 9);
    }
  }

  // fragment LDS offsets (swizzled)
  int aoffs[4], boffs[4];
#pragma unroll
  for (int m = 0; m < 4; ++m) {
    int R = (wr << 6) + (m << 4) + lrow;
    aoffs[m] = (R << 5) + ((lk ^ ((R >> 1) & 3)) << 3);
  }
#pragma unroll
  for (int n = 0; n < 4; ++n) {
    int R = (wc << 6) + (n << 4) + lrow;
    boffs[n] = (R << 5) + ((lk ^ ((R >> 1) & 3)) << 3);
  }

  f32x4 acc[4][4];
#pragma unroll
  for (int m = 0; m < 4; ++m)
#pragma unroll
    for (int n = 0; n < 4; ++n) acc[m][n] = (f32x4){0.f, 0.f, 0.f, 0.f};

  for (int k0 = 0; k0 < DIM; k0 += 32) {
    __syncthreads();
#pragma unroll
    for (int e = 0; e < 8; ++e)
      __builtin_amdgcn_global_load_lds(
          (const __attribute__((address_space(1))) void*)(srcs[e] + k0),
          (__attribute__((address_space(3))) void*)dsts[e], 16, 0, 0);
    __syncthreads();

    short8 fah[4], fal[4], fbh[4], fbl[4];
#pragma unroll
    for (int m = 0; m < 4; ++m) {
      fah[m] = *(const short8*)(sAh + aoffs[m]);
      fal[m] = *(const short8*)(sAl + aoffs[m]);
    }
#pragma unroll
    for (int n = 0; n < 4; ++n) {
      fbh[n] = *(const short8*)(sBh + boffs[n]);
      fbl[n] = *(const short8*)(sBl + boffs[n]);
    }
#pragma unroll
    for (int m = 0; m < 4; ++m)
#pragma unroll
      for (int n = 0; n < 4; ++n) {
        acc[m][n] = __builtin_amdgcn_mfma_f32_16x16x32_bf16(fah[m], fbh[n], acc[m][n], 0, 0, 0);
        acc[m][n] = __builtin_amdgcn_mfma_f32_16x16x32_bf16(fah[m], fbl[n], acc[m][n], 0, 0, 0);
        acc[m][n] = __builtin_amdgcn_mfma_f32_16x16x32_bf16(fal[m], fbh[n], acc[m][n], 0, 0, 0);
      }
  }

  // epilogue: d2 = a2 + b2 - 2ab, packed (d2,j) min over this block's 128 j's
#pragma unroll
  for (int m = 0; m < 4; ++m) {
    int ibase = i0 + (wr << 6) + (m << 4) + (lk << 2);
#pragma unroll
    for (int r = 0; r < 4; ++r) {
      int i = ibase + r;
      unsigned long long best = ~0ull;
      if (i < NP) {
        float ai = a2[i];
#pragma unroll
        for (int n = 0; n < 4; ++n) {
          int j = j0 + (wc << 6) + (n << 4) + lrow;
          float d2 = fmaxf(ai + b2[j] - 2.f * acc[m][n][r], 0.f);
          unsigned long long p = packdj(d2, j);
          best = (p < best) ? p : best;
        }
      }
#pragma unroll
      for (int mm = 1; mm < 16; mm <<= 1) {
        unsigned long long o = __shfl_xor(best, mm);
        best = (o < best) ? o : best;
      }
      if (lrow == 0 && i < NP)
        partial[(size_t)i * PCOLS + ntile * 2 + wc] = best;
    }
  }
}

// ================= reduce partial mins -> pmin[i] =================
__global__ __launch_bounds__(256) void k_reduce(const unsigned long long* __restrict__ partial,
                                                unsigned long long* __restrict__ pmin) {
  int i = (blockIdx.x << 2) | (threadIdx.x >> 6);
  int lane = threadIdx.x & 63;
  if (i >= NP) return;
  const unsigned long long* row = partial + (size_t)i * PCOLS;
  unsigned long long best = ~0ull;
  for (int e = lane; e < PCOLS; e += 64) {
    unsigned long long p = row[e];
    best = (p < best) ? p : best;
  }
#pragma unroll
  for (int m = 1; m < 64; m <<= 1) {
    unsigned long long o = __shfl_xor(best, m);
    best = (o < best) ? o : best;
  }
  if (lane == 0) pmin[i] = best;
}

// ======= fallback fp32 path kernels (used only if ws_size is too small) =======
__global__ __launch_bounds__(256) void k_norms(const float* __restrict__ patch,
                                               const float* __restrict__ lib,
                                               float* __restrict__ a2,
                                               float* __restrict__ b2) {
  int wave = (blockIdx.x << 2) | (threadIdx.x >> 6);
  int lane = threadIdx.x & 63;
  const int NR = NL + NP;
  if (wave >= NR) return;
  const float* src = (wave < NL) ? (lib + (size_t)wave * DIM)
                                 : (patch + (size_t)(wave - NL) * DIM);
  float s = 0.f;
#pragma unroll
  for (int m = 0; m < 6; ++m) { float v = src[lane + (m << 6)]; s += v * v; }
#pragma unroll
  for (int m = 1; m < 64; m <<= 1) s += __shfl_xor(s, m);
  if (lane == 0) { if (wave < NL) b2[wave] = s; else a2[wave - NL] = s; }
}

__global__ __launch_bounds__(256) void k_distmin(const float* __restrict__ patch,
                                                 const float* __restrict__ lib,
                                                 const float* __restrict__ a2,
                                                 const float* __restrict__ b2,
                                                 unsigned long long* __restrict__ pmin) {
  __shared__ float As[16][68];
  __shared__ float Bs[16][68];
  const int t = threadIdx.x;
  const int lr = t >> 2;
  const int lc = (t & 3) << 2;
  const int ti = t >> 4;
  const int tj = t & 15;
  const int i0 = blockIdx.y << 6;
  const int j0 = blockIdx.x << 6;
  const bool a_ok = (i0 + lr) < NP;
  const float* ap = patch + (size_t)(i0 + lr) * DIM + lc;
  const float* bp = lib + (size_t)(j0 + lr) * DIM + lc;

  float acc[4][4] = {};
  for (int k0 = 0; k0 < DIM; k0 += 16) {
    float4 avv = make_float4(0.f, 0.f, 0.f, 0.f);
    if (a_ok) avv = *(const float4*)(ap + k0);
    float4 bvv = *(const float4*)(bp + k0);
    __syncthreads();
    As[lc + 0][lr] = avv.x; As[lc + 1][lr] = avv.y;
    As[lc + 2][lr] = avv.z; As[lc + 3][lr] = avv.w;
    Bs[lc + 0][lr] = bvv.x; Bs[lc + 1][lr] = bvv.y;
    Bs[lc + 2][lr] = bvv.z; Bs[lc + 3][lr] = bvv.w;
    __syncthreads();
#pragma unroll
    for (int kk = 0; kk < 16; ++kk) {
      float4 a = *(const float4*)&As[kk][ti << 2];
      float4 b = *(const float4*)&Bs[kk][tj << 2];
      acc[0][0] += a.x * b.x; acc[0][1] += a.x * b.y; acc[0][2] += a.x * b.z; acc[0][3] += a.x * b.w;
      acc[1][0] += a.y * b.x; acc[1][1] += a.y * b.y; acc[1][2] += a.y * b.z; acc[1][3] += a.y * b.w;
      acc[2][0] += a.z * b.x; acc[2][1] += a.z * b.y; acc[2][2] += a.z * b.z; acc[2][3] += a.z * b.w;
      acc[3][0] += a.w * b.x; acc[3][1] += a.w * b.y; acc[3][2] += a.w * b.z; acc[3][3] += a.w * b.w;
    }
  }
#pragma unroll
  for (int r = 0; r < 4; ++r) {
    int i = i0 + (ti << 2) + r;
    unsigned long long best = ~0ull;
    if (i < NP) {
      float ai = a2[i];
#pragma unroll
      for (int c = 0; c < 4; ++c) {
        int j = j0 + (tj << 2) + c;
        float d2 = fmaxf(ai + b2[j] - 2.f * acc[r][c], 0.f);
        unsigned long long p = packdj(d2, j);
        best = (p < best) ? p : best;
      }
    }
#pragma unroll
    for (int m = 1; m < 16; m <<= 1) {
      unsigned long long o = __shfl_xor(best, m);
      best = (o < best) ? o : best;
    }
    if (tj == 0 && i < NP) atomicMin(pmin + i, best);
  }
}

// ---------- finalize1: min_val = sqrt(d2min); s_star/s_idx (jnp tie-break) ----------
__global__ __launch_bounds__(256) void k_final1(const unsigned long long* __restrict__ pmin,
                                                float* __restrict__ minval,
                                                float* __restrict__ scalf,
                                                int* __restrict__ scali) {
  __shared__ float sv[256];
  __shared__ int si[256];
  int t = threadIdx.x;
  float bv = -1.f; int bi = 1 << 30;
  for (int i = t; i < NP; i += 256) {
    unsigned long long p = pmin[i];
    float d2 = __uint_as_float((unsigned int)(p >> 32));
    float v = sqrtf(d2);
    minval[i] = v;
    if (v > bv) { bv = v; bi = i; }
  }
  sv[t] = bv; si[t] = bi;
  __syncthreads();
  for (int s = 128; s > 0; s >>= 1) {
    if (t < s) {
      if (sv[t + s] > sv[t] || (sv[t + s] == sv[t] && si[t + s] < si[t])) {
        sv[t] = sv[t + s]; si[t] = si[t + s];
      }
    }
    __syncthreads();
  }
  if (t == 0) {
    scalf[0] = sv[0];
    scali[0] = si[0];
    scali[1] = (int)(unsigned int)(pmin[si[0]] & 0xFFFFFFFFull);
  }
}

// ---------- w_dist from m_star to all lib rows; per-block top-3 ----------
__global__ __launch_bounds__(256) void k_wtop(const float* __restrict__ lib,
                                              const int* __restrict__ scali,
                                              unsigned long long* __restrict__ top3) {
  __shared__ unsigned long long sm[12];
  int wave = threadIdx.x >> 6, lane = threadIdx.x & 63;
  int jstar = scali[1];
  const float* ms = lib + (size_t)jstar * DIM;
  float m[6];
#pragma unroll
  for (int q = 0; q < 6; ++q) m[q] = ms[lane + (q << 6)];
  unsigned long long t0 = ~0ull, t1 = ~0ull, t2 = ~0ull;
  int gw = (blockIdx.x << 2) | wave;
  for (int j = gw; j < NL; j += WTOP_BLOCKS * 4) {
    const float* bp = lib + (size_t)j * DIM;
    float s = 0.f;
#pragma unroll
    for (int q = 0; q < 6; ++q) { float d = bp[lane + (q << 6)] - m[q]; s += d * d; }
#pragma unroll
    for (int mm = 1; mm < 64; mm <<= 1) s += __shfl_xor(s, mm);
    ins3(t0, t1, t2, packdj(fmaxf(s, 0.f), j));
  }
  if (lane == 0) { sm[wave * 3] = t0; sm[wave * 3 + 1] = t1; sm[wave * 3 + 2] = t2; }
  __syncthreads();
  if (threadIdx.x == 0) {
    unsigned long long a0 = ~0ull, a1 = ~0ull, a2v = ~0ull;
    for (int e = 0; e < 12; ++e) ins3(a0, a1, a2v, sm[e]);
    top3[blockIdx.x * 3 + 0] = a0;
    top3[blockIdx.x * 3 + 1] = a1;
    top3[blockIdx.x * 3 + 2] = a2v;
  }
}

// ---------- final s ----------
__global__ __launch_bounds__(256) void k_finals(const float* __restrict__ patch,
                                                const float* __restrict__ lib,
                                                const unsigned long long* __restrict__ top3,
                                                const float* __restrict__ scalf,
                                                const int* __restrict__ scali,
                                                float* __restrict__ out) {
  __shared__ unsigned long long sm[768];
  __shared__ int snn[2];
  __shared__ float sd[2];
  int t = threadIdx.x;
  unsigned long long t0 = ~0ull, t1 = ~0ull, t2 = ~0ull;
  for (int e = t; e < WTOP_BLOCKS * 3; e += 256) ins3(t0, t1, t2, top3[e]);
  sm[t] = t0; sm[256 + t] = t1; sm[512 + t] = t2;
  __syncthreads();
  if (t == 0) {
    unsigned long long a0 = ~0ull, a1 = ~0ull, a2v = ~0ull;
    for (int e = 0; e < 768; ++e) ins3(a0, a1, a2v, sm[e]);
    snn[0] = (int)(unsigned int)(a1 & 0xFFFFFFFFull);
    snn[1] = (int)(unsigned int)(a2v & 0xFFFFFFFFull);
  }
  __syncthreads();
  if (t < 128) {
    int wv = t >> 6, lane = t & 63;
    const float* mt = patch + (size_t)scali[0] * DIM;
    const float* bp = lib + (size_t)snn[wv] * DIM;
    float s = 0.f;
#pragma unroll
    for (int q = 0; q < 6; ++q) {
      float d = mt[lane + (q << 6)] - bp[lane + (q << 6)];
      s += d * d;
    }
#pragma unroll
    for (int mm = 1; mm < 64; mm <<= 1) s += __shfl_xor(s, mm);
    if (lane == 0) sd[wv] = sqrtf(fmaxf(s, 0.f));
  }
  __syncthreads();
  if (t == 0) {
    const float Ds = 19.595917942265423f;  // sqrt(384)
    float sstar = scalf[0];
    float w = 1.f - expf(sstar / Ds) / (expf(sd[0] / Ds) + expf(sd[1] / Ds));
    out[0] = w * sstar;
  }
}

// ---------- bilinear 28x28 -> 224x224 ----------
__global__ __launch_bounds__(256) void k_resize(const float* __restrict__ mv,
                                                float* __restrict__ out) {
  int o = blockIdx.x * 256 + threadIdx.x;
  if (o >= 224 * 224) return;
  int y = o / 224, x = o - y * 224;
  float sy = (y + 0.5f) * 0.125f - 0.5f;
  float sx = (x + 0.5f) * 0.125f - 0.5f;
  int y0 = (int)floorf(sy); float fy = sy - (float)y0;
  int x0 = (int)floorf(sx); float fx = sx - (float)x0;
  int y0c = max(y0, 0), y1c = min(y0 + 1, 27);
  int x0c = max(x0, 0), x1c = min(x0 + 1, 27);
  float v00 = mv[y0c * 28 + x0c], v01 = mv[y0c * 28 + x1c];
  float v10 = mv[y1c * 28 + x0c], v11 = mv[y1c * 28 + x1c];
  float v0 = v00 + fx * (v01 - v00);
  float v1 = v10 + fx * (v11 - v10);
  out[1 + o] = v0 + fy * (v1 - v0);
}

extern "C" void kernel_launch(void* const* d_in, const int* in_sizes, int n_in,
                              void* d_out, int out_size, void* d_ws, size_t ws_size,
                              hipStream_t stream) {
  const float* patch = (const float*)d_in[0];
  const float* lib = (const float*)d_in[1];
  float* out = (float*)d_out;
  char* ws = (char*)d_ws;

  const size_t SZ_BPLANE = (size_t)NLPAD * DIM * 2;     // 153,649,152
  const size_t SZ_APLANE = (size_t)MPAD * DIM * 2;      // 688,128
  const size_t SZ_PART = (size_t)NP * PCOLS * 8;        // 19,606,272
  const size_t NEED = 2 * SZ_BPLANE + 2 * SZ_APLANE + SZ_PART + 2 * 1024 * 1024;

  if (ws_size >= NEED) {
    size_t off = 0;
    unsigned short* Bh = (unsigned short*)(ws + off); off += SZ_BPLANE;
    unsigned short* Bl = (unsigned short*)(ws + off); off += SZ_BPLANE;
    unsigned short* Ah = (unsigned short*)(ws + off); off += SZ_APLANE;
    unsigned short* Al = (unsigned short*)(ws + off); off += SZ_APLANE;
    unsigned long long* partial = (unsigned long long*)(ws + off); off += SZ_PART;
    float* b2 = (float*)(ws + off); off += (size_t)NLPAD * 4;
    float* a2 = (float*)(ws + off); off += (size_t)MPAD * 4;
    unsigned long long* pmin = (unsigned long long*)(ws + off); off += NP * 8;
    unsigned long long* top3 = (unsigned long long*)(ws + off); off += WTOP_BLOCKS * 3 * 8;
    float* minval = (float*)(ws + off); off += NP * 4;
    float* scalf = (float*)(ws + off); off += 16;
    int* scali = (int*)(ws + off); off += 16;

    k_prep_a<<<MPAD / 4, 256, 0, stream>>>(patch, Ah, Al, a2);
    k_prep_b<<<NLPAD / 4, 256, 0, stream>>>(lib, Bh, Bl, b2);
    k_gemm<<<MTILES * NTILES, 256, 0, stream>>>(Ah, Al, Bh, Bl, a2, b2, partial);
    k_reduce<<<(NP + 3) / 4, 256, 0, stream>>>(partial, pmin);
    k_final1<<<1, 256, 0, stream>>>(pmin, minval, scalf, scali);
    k_wtop<<<WTOP_BLOCKS, 256, 0, stream>>>(lib, scali, top3);
    k_finals<<<1, 256, 0, stream>>>(patch, lib, top3, scalf, scali, out);
    k_resize<<<(224 * 224 + 255) / 256, 256, 0, stream>>>(minval, out);
  } else {
    // fallback: fp32 VALU path (verified R1)
    float* b2 = (float*)ws;
    float* a2 = (float*)(ws + 800000);
    unsigned long long* pmin = (unsigned long long*)(ws + 803200);
    unsigned long long* top3 = (unsigned long long*)(ws + 809472);
    float* minval = (float*)(ws + 821760);
    float* scalf = (float*)(ws + 824896);
    int* scali = (int*)(ws + 824912);

    hipMemsetAsync(pmin, 0xFF, NP * sizeof(unsigned long long), stream);
    k_norms<<<(NL + NP + 3) / 4, 256, 0, stream>>>(patch, lib, a2, b2);
    dim3 grid(NL / 64, (NP + 63) / 64);
    k_distmin<<<grid, 256, 0, stream>>>(patch, lib, a2, b2, pmin);
    k_final1<<<1, 256, 0, stream>>>(pmin, minval, scalf, scali);
    k_wtop<<<WTOP_BLOCKS, 256, 0, stream>>>(lib, scali, top3);
    k_finals<<<1, 256, 0, stream>>>(patch, lib, top3, scalf, scali, out);
    k_resize<<<(224 * 224 + 255) / 256, 256, 0, stream>>>(minval, out);
  }
}

// Round 3
// 647.009 us; speedup vs baseline: 3.5188x; 1.2426x over previous
//
#include <hip/hip_runtime.h>

#define NP 784
#define DIM 384
#define NL 200000
#define WTOP_BLOCKS 512

#define BM 128
#define BN 128
#define MTILES 7
#define NTILES 1563
#define MPAD (MTILES * BM)    // 896
#define NLPAD (NTILES * BN)   // 200064
#define PCOLS (NTILES * 2)    // 3126 granules of 64 j's per i
#define DELTA2 4.0f           // 2*delta margin on approx d2
#define RESCORE_WAVES 2048

typedef __attribute__((ext_vector_type(8))) short short8;
typedef __attribute__((ext_vector_type(4))) float f32x4;

__device__ __forceinline__ unsigned long long packdj(float d2, int j) {
  return ((unsigned long long)__float_as_uint(d2) << 32) | (unsigned int)j;
}

__device__ __forceinline__ void ins3(unsigned long long &t0, unsigned long long &t1,
                                     unsigned long long &t2, unsigned long long p) {
  if (p < t0) { t2 = t1; t1 = t0; t0 = p; }
  else if (p < t1) { t2 = t1; t1 = p; }
  else if (p < t2) { t2 = p; }
}

__device__ __forceinline__ unsigned short bf16rn(float x) {
  unsigned u = __float_as_uint(x);
  unsigned r = (u + 0x7fffu + ((u >> 16) & 1u)) >> 16;
  return (unsigned short)r;
}

// ================= prep A: patch -> Ah bf16 + a2 (exact fp32) =================
__global__ __launch_bounds__(256) void k_prep_a(const float* __restrict__ patch,
                                                unsigned short* __restrict__ Ah,
                                                float* __restrict__ a2) {
  int i = (blockIdx.x << 2) | (threadIdx.x >> 6);
  int lane = threadIdx.x & 63;
  if (i >= MPAD) return;
  if (i < NP) {
    float s = 0.f;
#pragma unroll
    for (int q = 0; q < 6; ++q) {
      float x = patch[(size_t)i * DIM + lane + (q << 6)];
      s += x * x;
      Ah[(size_t)i * DIM + lane + (q << 6)] = bf16rn(x);
    }
#pragma unroll
    for (int m = 1; m < 64; m <<= 1) s += __shfl_xor(s, m);
    if (lane == 0) a2[i] = s;
  } else {
#pragma unroll
    for (int q = 0; q < 6; ++q) Ah[(size_t)i * DIM + lane + (q << 6)] = 0;
  }
}

// ================= prep B: lib -> Bh bf16 + b2 (pad rows: zero, b2=+inf) ======
__global__ __launch_bounds__(256) void k_prep_b(const float* __restrict__ lib,
                                                unsigned short* __restrict__ Bh,
                                                float* __restrict__ b2) {
  int j = (blockIdx.x << 2) | (threadIdx.x >> 6);
  int lane = threadIdx.x & 63;
  if (j >= NLPAD) return;
  if (j < NL) {
    float s = 0.f;
#pragma unroll
    for (int q = 0; q < 6; ++q) {
      float x = lib[(size_t)j * DIM + lane + (q << 6)];
      s += x * x;
      Bh[(size_t)j * DIM + lane + (q << 6)] = bf16rn(x);
    }
#pragma unroll
    for (int m = 1; m < 64; m <<= 1) s += __shfl_xor(s, m);
    if (lane == 0) b2[j] = s;
  } else {
#pragma unroll
    for (int q = 0; q < 6; ++q) Bh[(size_t)j * DIM + lane + (q << 6)] = 0;
    if (lane == 0) b2[j] = INFINITY;
  }
}

// ============== main: 128x128 MFMA GEMM (hi-only bf16) + fused approx packed min =========
__global__ __launch_bounds__(256, 2) void k_gemm(const unsigned short* __restrict__ Ah,
                                                 const unsigned short* __restrict__ Bh,
                                                 const float* __restrict__ a2,
                                                 const float* __restrict__ b2,
                                                 unsigned long long* __restrict__ partial) {
  __shared__ short sAh[4096], sBh[4096];

  const int TOT = MTILES * NTILES;
  const int q8 = TOT >> 3, r8 = TOT & 7;
  int xcd = blockIdx.x & 7, seq = blockIdx.x >> 3;
  int wg = (xcd < r8 ? xcd * (q8 + 1) : r8 * (q8 + 1) + (xcd - r8) * q8) + seq;
  int ntile = wg / MTILES;
  int mtile = wg - ntile * MTILES;
  const int i0 = mtile * BM;
  const int j0 = ntile * BN;

  const int t = threadIdx.x;
  const int w = t >> 6, lane = t & 63;
  const int wr = w >> 1, wc = w & 1;
  const int lrow = lane & 15, lk = lane >> 4;

  const unsigned short* srcs[4];
  short* dsts[4];
  {
    int dbase = w << 10;
#pragma unroll
    for (int p = 0; p < 2; ++p) {
      int c = (w << 7) + (p << 6) + lane;
      int row = c >> 2, kb = c & 3;
      int ks = ((kb ^ ((row >> 1) & 3)) << 3);
      srcs[0 + p] = Ah + (size_t)(i0 + row) * DIM + ks;
      srcs[2 + p] = Bh + (size_t)(j0 + row) * DIM + ks;
      dsts[0 + p] = sAh + dbase + (p << 9);
      dsts[2 + p] = sBh + dbase + (p << 9);
    }
  }

  int aoffs[4], boffs[4];
#pragma unroll
  for (int m = 0; m < 4; ++m) {
    int R = (wr << 6) + (m << 4) + lrow;
    aoffs[m] = (R << 5) + ((lk ^ ((R >> 1) & 3)) << 3);
  }
#pragma unroll
  for (int n = 0; n < 4; ++n) {
    int R = (wc << 6) + (n << 4) + lrow;
    boffs[n] = (R << 5) + ((lk ^ ((R >> 1) & 3)) << 3);
  }

  f32x4 acc[4][4];
#pragma unroll
  for (int m = 0; m < 4; ++m)
#pragma unroll
    for (int n = 0; n < 4; ++n) acc[m][n] = (f32x4){0.f, 0.f, 0.f, 0.f};

  for (int k0 = 0; k0 < DIM; k0 += 32) {
    __syncthreads();
#pragma unroll
    for (int e = 0; e < 4; ++e)
      __builtin_amdgcn_global_load_lds(
          (const __attribute__((address_space(1))) void*)(srcs[e] + k0),
          (__attribute__((address_space(3))) void*)dsts[e], 16, 0, 0);
    __syncthreads();

    short8 fah[4], fbh[4];
#pragma unroll
    for (int m = 0; m < 4; ++m) fah[m] = *(const short8*)(sAh + aoffs[m]);
#pragma unroll
    for (int n = 0; n < 4; ++n) fbh[n] = *(const short8*)(sBh + boffs[n]);
#pragma unroll
    for (int m = 0; m < 4; ++m)
#pragma unroll
      for (int n = 0; n < 4; ++n)
        acc[m][n] = __builtin_amdgcn_mfma_f32_16x16x32_bf16(fah[m], fbh[n], acc[m][n], 0, 0, 0);
  }

  // epilogue: approx d2, packed (d2,j) min per (i, 64-j granule)
#pragma unroll
  for (int m = 0; m < 4; ++m) {
    int ibase = i0 + (wr << 6) + (m << 4) + (lk << 2);
#pragma unroll
    for (int r = 0; r < 4; ++r) {
      int i = ibase + r;
      unsigned long long best = ~0ull;
      if (i < NP) {
        float ai = a2[i];
#pragma unroll
        for (int n = 0; n < 4; ++n) {
          int j = j0 + (wc << 6) + (n << 4) + lrow;
          float d2 = fmaxf(ai + b2[j] - 2.f * acc[m][n][r], 0.f);
          unsigned long long p = packdj(d2, j);
          best = (p < best) ? p : best;
        }
      }
#pragma unroll
      for (int mm = 1; mm < 16; mm <<= 1) {
        unsigned long long o = __shfl_xor(best, mm);
        best = (o < best) ? o : best;
      }
      if (lrow == 0 && i < NP)
        partial[(size_t)i * PCOLS + ntile * 2 + wc] = best;
    }
  }
}

// ===== scan granule mins per i; select candidates within margin -> compacted list =====
__global__ __launch_bounds__(256) void k_scan_select(const unsigned long long* __restrict__ partial,
                                                     unsigned int* __restrict__ list,
                                                     unsigned int* __restrict__ cnt) {
  __shared__ unsigned long long red[256];
  __shared__ float thr;
  int i = blockIdx.x;
  int t = threadIdx.x;
  const unsigned long long* row = partial + (size_t)i * PCOLS;
  unsigned long long best = ~0ull;
  for (int e = t; e < PCOLS; e += 256) {
    unsigned long long p = row[e];
    best = (p < best) ? p : best;
  }
  red[t] = best;
  __syncthreads();
  for (int s = 128; s > 0; s >>= 1) {
    if (t < s) { unsigned long long o = red[t + s]; if (o < red[t]) red[t] = o; }
    __syncthreads();
  }
  if (t == 0) thr = __uint_as_float((unsigned int)(red[0] >> 32)) + DELTA2;
  __syncthreads();
  float th = thr;
  for (int e = t; e < PCOLS; e += 256) {
    float d = __uint_as_float((unsigned int)(row[e] >> 32));
    if (d <= th) {
      unsigned int pos = atomicAdd(cnt, 1u);
      list[pos] = ((unsigned int)i << 12) | (unsigned int)e;
    }
  }
}

// ===== exact fp32 rescore of candidate granules -> pmin (packed atomicMin) =====
__global__ __launch_bounds__(256) void k_rescore(const unsigned int* __restrict__ list,
                                                 const unsigned int* __restrict__ cnt,
                                                 const float* __restrict__ patch,
                                                 const float* __restrict__ lib,
                                                 const float* __restrict__ a2,
                                                 const float* __restrict__ b2,
                                                 unsigned long long* __restrict__ pmin) {
  int wid = (blockIdx.x << 2) | (threadIdx.x >> 6);
  int lane = threadIdx.x & 63;
  int n = (int)*cnt;
  for (int c = wid; c < n; c += RESCORE_WAVES) {
    unsigned int e = list[c];
    int i = (int)(e >> 12);
    int g = (int)(e & 4095u);
    int j = (g << 6) + lane;
    unsigned long long best = ~0ull;
    if (j < NL) {
      const float* pr = patch + (size_t)i * DIM;
      const float* lr = lib + (size_t)j * DIM;
      float d0 = 0.f, d1 = 0.f, d2s = 0.f, d3 = 0.f;
#pragma unroll 8
      for (int k = 0; k < DIM; k += 4) {
        float4 lv = *(const float4*)(lr + k);
        float4 pv = *(const float4*)(pr + k);
        d0 = fmaf(lv.x, pv.x, d0);
        d1 = fmaf(lv.y, pv.y, d1);
        d2s = fmaf(lv.z, pv.z, d2s);
        d3 = fmaf(lv.w, pv.w, d3);
      }
      float dot = (d0 + d1) + (d2s + d3);
      float d2 = fmaxf(a2[i] + b2[j] - 2.f * dot, 0.f);
      best = packdj(d2, j);
    }
#pragma unroll
    for (int mm = 1; mm < 64; mm <<= 1) {
      unsigned long long o = __shfl_xor(best, mm);
      best = (o < best) ? o : best;
    }
    if (lane == 0) atomicMin(pmin + i, best);
  }
}

// ---------- finalize1: min_val = sqrt(d2min); s_star/s_idx (jnp tie-break) ----------
__global__ __launch_bounds__(256) void k_final1(const unsigned long long* __restrict__ pmin,
                                                float* __restrict__ minval,
                                                float* __restrict__ scalf,
                                                int* __restrict__ scali) {
  __shared__ float sv[256];
  __shared__ int si[256];
  int t = threadIdx.x;
  float bv = -1.f; int bi = 1 << 30;
  for (int i = t; i < NP; i += 256) {
    unsigned long long p = pmin[i];
    float d2 = __uint_as_float((unsigned int)(p >> 32));
    float v = sqrtf(d2);
    minval[i] = v;
    if (v > bv) { bv = v; bi = i; }
  }
  sv[t] = bv; si[t] = bi;
  __syncthreads();
  for (int s = 128; s > 0; s >>= 1) {
    if (t < s) {
      if (sv[t + s] > sv[t] || (sv[t + s] == sv[t] && si[t + s] < si[t])) {
        sv[t] = sv[t + s]; si[t] = si[t + s];
      }
    }
    __syncthreads();
  }
  if (t == 0) {
    scalf[0] = sv[0];
    scali[0] = si[0];
    scali[1] = (int)(unsigned int)(pmin[si[0]] & 0xFFFFFFFFull);
  }
}

// ---------- w_dist from m_star to all lib rows; per-block top-3 ----------
__global__ __launch_bounds__(256) void k_wtop(const float* __restrict__ lib,
                                              const int* __restrict__ scali,
                                              unsigned long long* __restrict__ top3) {
  __shared__ unsigned long long sm[12];
  int wave = threadIdx.x >> 6, lane = threadIdx.x & 63;
  int jstar = scali[1];
  const float* ms = lib + (size_t)jstar * DIM;
  float m[6];
#pragma unroll
  for (int q = 0; q < 6; ++q) m[q] = ms[lane + (q << 6)];
  unsigned long long t0 = ~0ull, t1 = ~0ull, t2 = ~0ull;
  int gw = (blockIdx.x << 2) | wave;
  for (int j = gw; j < NL; j += WTOP_BLOCKS * 4) {
    const float* bp = lib + (size_t)j * DIM;
    float s = 0.f;
#pragma unroll
    for (int q = 0; q < 6; ++q) { float d = bp[lane + (q << 6)] - m[q]; s += d * d; }
#pragma unroll
    for (int mm = 1; mm < 64; mm <<= 1) s += __shfl_xor(s, mm);
    ins3(t0, t1, t2, packdj(fmaxf(s, 0.f), j));
  }
  if (lane == 0) { sm[wave * 3] = t0; sm[wave * 3 + 1] = t1; sm[wave * 3 + 2] = t2; }
  __syncthreads();
  if (threadIdx.x == 0) {
    unsigned long long a0 = ~0ull, a1 = ~0ull, a2v = ~0ull;
    for (int e = 0; e < 12; ++e) ins3(a0, a1, a2v, sm[e]);
    top3[blockIdx.x * 3 + 0] = a0;
    top3[blockIdx.x * 3 + 1] = a1;
    top3[blockIdx.x * 3 + 2] = a2v;
  }
}

// ---------- final s ----------
__global__ __launch_bounds__(256) void k_finals(const float* __restrict__ patch,
                                                const float* __restrict__ lib,
                                                const unsigned long long* __restrict__ top3,
                                                const float* __restrict__ scalf,
                                                const int* __restrict__ scali,
                                                float* __restrict__ out) {
  __shared__ unsigned long long sm[768];
  __shared__ int snn[2];
  __shared__ float sd[2];
  int t = threadIdx.x;
  unsigned long long t0 = ~0ull, t1 = ~0ull, t2 = ~0ull;
  for (int e = t; e < WTOP_BLOCKS * 3; e += 256) ins3(t0, t1, t2, top3[e]);
  sm[t] = t0; sm[256 + t] = t1; sm[512 + t] = t2;
  __syncthreads();
  if (t == 0) {
    unsigned long long a0 = ~0ull, a1 = ~0ull, a2v = ~0ull;
    for (int e = 0; e < 768; ++e) ins3(a0, a1, a2v, sm[e]);
    snn[0] = (int)(unsigned int)(a1 & 0xFFFFFFFFull);
    snn[1] = (int)(unsigned int)(a2v & 0xFFFFFFFFull);
  }
  __syncthreads();
  if (t < 128) {
    int wv = t >> 6, lane = t & 63;
    const float* mt = patch + (size_t)scali[0] * DIM;
    const float* bp = lib + (size_t)snn[wv] * DIM;
    float s = 0.f;
#pragma unroll
    for (int q = 0; q < 6; ++q) {
      float d = mt[lane + (q << 6)] - bp[lane + (q << 6)];
      s += d * d;
    }
#pragma unroll
    for (int mm = 1; mm < 64; mm <<= 1) s += __shfl_xor(s, mm);
    if (lane == 0) sd[wv] = sqrtf(fmaxf(s, 0.f));
  }
  __syncthreads();
  if (t == 0) {
    const float Ds = 19.595917942265423f;  // sqrt(384)
    float sstar = scalf[0];
    float w = 1.f - expf(sstar / Ds) / (expf(sd[0] / Ds) + expf(sd[1] / Ds));
    out[0] = w * sstar;
  }
}

// ---------- bilinear 28x28 -> 224x224 ----------
__global__ __launch_bounds__(256) void k_resize(const float* __restrict__ mv,
                                                float* __restrict__ out) {
  int o = blockIdx.x * 256 + threadIdx.x;
  if (o >= 224 * 224) return;
  int y = o / 224, x = o - y * 224;
  float sy = (y + 0.5f) * 0.125f - 0.5f;
  float sx = (x + 0.5f) * 0.125f - 0.5f;
  int y0 = (int)floorf(sy); float fy = sy - (float)y0;
  int x0 = (int)floorf(sx); float fx = sx - (float)x0;
  int y0c = max(y0, 0), y1c = min(y0 + 1, 27);
  int x0c = max(x0, 0), x1c = min(x0 + 1, 27);
  float v00 = mv[y0c * 28 + x0c], v01 = mv[y0c * 28 + x1c];
  float v10 = mv[y1c * 28 + x0c], v11 = mv[y1c * 28 + x1c];
  float v0 = v00 + fx * (v01 - v00);
  float v1 = v10 + fx * (v11 - v10);
  out[1 + o] = v0 + fy * (v1 - v0);
}

// ======= fallback fp32 path kernels (used only if ws_size is too small) =======
__global__ __launch_bounds__(256) void k_norms(const float* __restrict__ patch,
                                               const float* __restrict__ lib,
                                               float* __restrict__ a2,
                                               float* __restrict__ b2) {
  int wave = (blockIdx.x << 2) | (threadIdx.x >> 6);
  int lane = threadIdx.x & 63;
  const int NR = NL + NP;
  if (wave >= NR) return;
  const float* src = (wave < NL) ? (lib + (size_t)wave * DIM)
                                 : (patch + (size_t)(wave - NL) * DIM);
  float s = 0.f;
#pragma unroll
  for (int m = 0; m < 6; ++m) { float v = src[lane + (m << 6)]; s += v * v; }
#pragma unroll
  for (int m = 1; m < 64; m <<= 1) s += __shfl_xor(s, m);
  if (lane == 0) { if (wave < NL) b2[wave] = s; else a2[wave - NL] = s; }
}

__global__ __launch_bounds__(256) void k_distmin(const float* __restrict__ patch,
                                                 const float* __restrict__ lib,
                                                 const float* __restrict__ a2,
                                                 const float* __restrict__ b2,
                                                 unsigned long long* __restrict__ pmin) {
  __shared__ float As[16][68];
  __shared__ float Bs[16][68];
  const int t = threadIdx.x;
  const int lr = t >> 2;
  const int lc = (t & 3) << 2;
  const int ti = t >> 4;
  const int tj = t & 15;
  const int i0 = blockIdx.y << 6;
  const int j0 = blockIdx.x << 6;
  const bool a_ok = (i0 + lr) < NP;
  const float* ap = patch + (size_t)(i0 + lr) * DIM + lc;
  const float* bp = lib + (size_t)(j0 + lr) * DIM + lc;

  float acc[4][4] = {};
  for (int k0 = 0; k0 < DIM; k0 += 16) {
    float4 avv = make_float4(0.f, 0.f, 0.f, 0.f);
    if (a_ok) avv = *(const float4*)(ap + k0);
    float4 bvv = *(const float4*)(bp + k0);
    __syncthreads();
    As[lc + 0][lr] = avv.x; As[lc + 1][lr] = avv.y;
    As[lc + 2][lr] = avv.z; As[lc + 3][lr] = avv.w;
    Bs[lc + 0][lr] = bvv.x; Bs[lc + 1][lr] = bvv.y;
    Bs[lc + 2][lr] = bvv.z; Bs[lc + 3][lr] = bvv.w;
    __syncthreads();
#pragma unroll
    for (int kk = 0; kk < 16; ++kk) {
      float4 a = *(const float4*)&As[kk][ti << 2];
      float4 b = *(const float4*)&Bs[kk][tj << 2];
      acc[0][0] += a.x * b.x; acc[0][1] += a.x * b.y; acc[0][2] += a.x * b.z; acc[0][3] += a.x * b.w;
      acc[1][0] += a.y * b.x; acc[1][1] += a.y * b.y; acc[1][2] += a.y * b.z; acc[1][3] += a.y * b.w;
      acc[2][0] += a.z * b.x; acc[2][1] += a.z * b.y; acc[2][2] += a.z * b.z; acc[2][3] += a.z * b.w;
      acc[3][0] += a.w * b.x; acc[3][1] += a.w * b.y; acc[3][2] += a.w * b.z; acc[3][3] += a.w * b.w;
    }
  }
#pragma unroll
  for (int r = 0; r < 4; ++r) {
    int i = i0 + (ti << 2) + r;
    unsigned long long best = ~0ull;
    if (i < NP) {
      float ai = a2[i];
#pragma unroll
      for (int c = 0; c < 4; ++c) {
        int j = j0 + (tj << 2) + c;
        float d2 = fmaxf(ai + b2[j] - 2.f * acc[r][c], 0.f);
        unsigned long long p = packdj(d2, j);
        best = (p < best) ? p : best;
      }
    }
#pragma unroll
    for (int m = 1; m < 16; m <<= 1) {
      unsigned long long o = __shfl_xor(best, m);
      best = (o < best) ? o : best;
    }
    if (tj == 0 && i < NP) atomicMin(pmin + i, best);
  }
}

extern "C" void kernel_launch(void* const* d_in, const int* in_sizes, int n_in,
                              void* d_out, int out_size, void* d_ws, size_t ws_size,
                              hipStream_t stream) {
  const float* patch = (const float*)d_in[0];
  const float* lib = (const float*)d_in[1];
  float* out = (float*)d_out;
  char* ws = (char*)d_ws;

  const size_t SZ_BPLANE = (size_t)NLPAD * DIM * 2;          // 153,649,152
  const size_t SZ_APLANE = (size_t)MPAD * DIM * 2;           // 688,128
  const size_t SZ_PART = (size_t)NP * PCOLS * 8;             // 19,606,272
  const size_t SZ_LIST = (size_t)NP * PCOLS * 4;             // 9,803,136
  const size_t NEED = SZ_BPLANE + SZ_APLANE + SZ_PART + SZ_LIST + 2 * 1024 * 1024;

  if (ws_size >= NEED) {
    size_t off = 0;
    unsigned short* Bh = (unsigned short*)(ws + off); off += SZ_BPLANE;
    unsigned short* Ah = (unsigned short*)(ws + off); off += SZ_APLANE;
    unsigned long long* partial = (unsigned long long*)(ws + off); off += SZ_PART;
    unsigned int* list = (unsigned int*)(ws + off); off += SZ_LIST;
    float* b2 = (float*)(ws + off); off += (size_t)NLPAD * 4;
    float* a2 = (float*)(ws + off); off += (size_t)MPAD * 4;
    unsigned long long* pmin = (unsigned long long*)(ws + off); off += NP * 8;
    unsigned long long* top3 = (unsigned long long*)(ws + off); off += WTOP_BLOCKS * 3 * 8;
    float* minval = (float*)(ws + off); off += NP * 4;
    float* scalf = (float*)(ws + off); off += 16;
    int* scali = (int*)(ws + off); off += 16;
    unsigned int* cnt = (unsigned int*)(ws + off); off += 16;

    hipMemsetAsync(pmin, 0xFF, NP * sizeof(unsigned long long), stream);
    hipMemsetAsync(cnt, 0, sizeof(unsigned int), stream);

    k_prep_a<<<MPAD / 4, 256, 0, stream>>>(patch, Ah, a2);
    k_prep_b<<<NLPAD / 4, 256, 0, stream>>>(lib, Bh, b2);
    k_gemm<<<MTILES * NTILES, 256, 0, stream>>>(Ah, Bh, a2, b2, partial);
    k_scan_select<<<NP, 256, 0, stream>>>(partial, list, cnt);
    k_rescore<<<RESCORE_WAVES / 4, 256, 0, stream>>>(list, cnt, patch, lib, a2, b2, pmin);
    k_final1<<<1, 256, 0, stream>>>(pmin, minval, scalf, scali);
    k_wtop<<<WTOP_BLOCKS, 256, 0, stream>>>(lib, scali, top3);
    k_finals<<<1, 256, 0, stream>>>(patch, lib, top3, scalf, scali, out);
    k_resize<<<(224 * 224 + 255) / 256, 256, 0, stream>>>(minval, out);
  } else {
    // fallback: fp32 VALU path (verified R1)
    float* b2 = (float*)ws;
    float* a2 = (float*)(ws + 800000);
    unsigned long long* pmin = (unsigned long long*)(ws + 803200);
    unsigned long long* top3 = (unsigned long long*)(ws + 809472);
    float* minval = (float*)(ws + 821760);
    float* scalf = (float*)(ws + 824896);
    int* scali = (int*)(ws + 824912);

    hipMemsetAsync(pmin, 0xFF, NP * sizeof(unsigned long long), stream);
    k_norms<<<(NL + NP + 3) / 4, 256, 0, stream>>>(patch, lib, a2, b2);
    dim3 grid(NL / 64, (NP + 63) / 64);
    k_distmin<<<grid, 256, 0, stream>>>(patch, lib, a2, b2, pmin);
    k_final1<<<1, 256, 0, stream>>>(pmin, minval, scalf, scali);
    k_wtop<<<WTOP_BLOCKS, 256, 0, stream>>>(lib, scali, top3);
    k_finals<<<1, 256, 0, stream>>>(patch, lib, top3, scalf, scali, out);
    k_resize<<<(224 * 224 + 255) / 256, 256, 0, stream>>>(minval, out);
  }
}